// Round 5
// baseline (927.682 us; speedup 1.0000x reference)
//
#include <hip/hip_runtime.h>
#include <math.h>

#define PW 32
#define PL 64
#define PK 512
#define PN 64
// vectors (replica configurations) total: PW*PL*PK = 1,048,576

// 0/1 mask bit -> f64 1.0/0.0 via scalar cselect (bit pattern of 1.0)
__device__ __forceinline__ double selbit(unsigned long long m, int i) {
    unsigned long long d = ((m >> i) & 1ull) ? 0x3FF0000000000000ull : 0ull;
    return __builtin_bit_cast(double, d);
}

// ---------------- Kernel 1: energies ----------------
// One wave per chunk of VPW vectors (same w). Lane j holds Q[w][:, j] as f64
// in 64 named register variables, PINNED via opaque inline asm (rounds 3/4
// lesson: the scheduler SINKS loop-invariant global loads back into the loop
// to cut register pressure — VGPR stayed 76 and every q was an L1 reload.
// "+v" asm makes the value's def un-rematerializable, forcing VGPR residency).
constexpr int VPW = 64;

#define DECLQ(i) double q##i = (double)Qw[(i) * 64 + lane]; \
                 asm volatile("" : "+v"(q##i));
#define DECLQ8(a,b,c,d,e,f,g,h) DECLQ(a) DECLQ(b) DECLQ(c) DECLQ(d) DECLQ(e) DECLQ(f) DECLQ(g) DECLQ(h)

// accumulate 4 bits into the 4 chains — same i->chain mapping (i&3) and same
// per-chain order as rounds 2-4, so f64 results are bit-identical (mask safety).
#define STEP4(i0,i1,i2,i3) \
    a0 = __builtin_fma(selbit(m, i0), q##i0, a0); \
    a1 = __builtin_fma(selbit(m, i1), q##i1, a1); \
    a2 = __builtin_fma(selbit(m, i2), q##i2, a2); \
    a3 = __builtin_fma(selbit(m, i3), q##i3, a3);

__global__ __launch_bounds__(256, 2) void energies_kernel(
    const float* __restrict__ states, const float* __restrict__ Q,
    float* __restrict__ e_out, double* __restrict__ e64)
{
    const int wave = (blockIdx.x * blockDim.x + threadIdx.x) >> 6;
    const int lane = threadIdx.x & 63;
    const int waves_per_w = (PL * PK) / VPW;   // 512
    const int w = wave / waves_per_w;
    const int chunk = wave % waves_per_w;

    const float* Qw = Q + (long)w * PN * PN;
    DECLQ8( 0, 1, 2, 3, 4, 5, 6, 7)
    DECLQ8( 8, 9,10,11,12,13,14,15)
    DECLQ8(16,17,18,19,20,21,22,23)
    DECLQ8(24,25,26,27,28,29,30,31)
    DECLQ8(32,33,34,35,36,37,38,39)
    DECLQ8(40,41,42,43,44,45,46,47)
    DECLQ8(48,49,50,51,52,53,54,55)
    DECLQ8(56,57,58,59,60,61,62,63)

    const long base_v = (long)w * (PL * PK) + (long)chunk * VPW;
    const float* sp = states + base_v * PN + lane;

    float s = sp[0];
    for (int t = 0; t < VPW; ++t) {
        // prefetch next vector's element (independent; scheduler hoists it)
        float snext = (t + 1 < VPW) ? sp[(long)(t + 1) * PN] : 0.0f;

        const unsigned long long m = __ballot(s != 0.0f); // wave-uniform mask

        double a0 = 0.0, a1 = 0.0, a2 = 0.0, a3 = 0.0;
        STEP4( 0, 1, 2, 3)  STEP4( 4, 5, 6, 7)
        STEP4( 8, 9,10,11)  STEP4(12,13,14,15)
        STEP4(16,17,18,19)  STEP4(20,21,22,23)
        STEP4(24,25,26,27)  STEP4(28,29,30,31)
        STEP4(32,33,34,35)  STEP4(36,37,38,39)
        STEP4(40,41,42,43)  STEP4(44,45,46,47)
        STEP4(48,49,50,51)  STEP4(52,53,54,55)
        STEP4(56,57,58,59)  STEP4(60,61,62,63)
        const double colsum = (a0 + a1) + (a2 + a3);

        // lane j contributes only if s_j != 0 ; s is exactly 0.0f or 1.0f
        double e = colsum * (double)s;
#pragma unroll
        for (int off = 32; off > 0; off >>= 1)
            e += __shfl_down(e, off, 64);

        if (lane == 0) {
            e64[base_v + t]   = e;
            e_out[base_v + t] = (float)e;
        }
        s = snext;
    }
}

// ---------------- Kernel 2: exchange masks ----------------
__global__ __launch_bounds__(256) void mask_kernel(
    const double* __restrict__ e64, const float* __restrict__ beta,
    const float* __restrict__ u, unsigned char* __restrict__ mask)
{
    const int idx = blockIdx.x * blockDim.x + threadIdx.x;
    if (idx >= PW * (PL - 1) * PK) return;
    const int k = idx % PK;
    const int m = (idx / PK) % (PL - 1);
    const int w = idx / (PK * (PL - 1));
    const long e1 = ((long)w * PL + m) * PK + k;
    const double db = (double)beta[m + 1] - (double)beta[m];
    const double delta = (e64[e1 + PK] - e64[e1]) * db;
    mask[idx] = ((double)u[idx] < exp(delta)) ? 1 : 0;
}

// ---------------- Kernel 3: masked replica swap ----------------
// new[w,0]   = mask[w,0]   ? s[w,1]   : s[w,0]
// new[w,l>0] = mask[w,l-1] ? s[w,l-1] : s[w,l]
// Block = 32 consecutive rows (same w,l; k 32-aligned). Each thread owns
// row r = tid>>3 and two float4s; loads its own mask byte (8 lanes share one
// byte -> L1 broadcast). No LDS, no barrier — round-4's tid<32 stage +
// __syncthreads serialized the dependent mask->copy chain.
__global__ __launch_bounds__(256) void swap_kernel(
    const float* __restrict__ states, const unsigned char* __restrict__ mask,
    float* __restrict__ out)
{
    const long rowBase = (long)blockIdx.x * 32;     // (w*L + l)*K + k0
    const int w  = (int)(rowBase >> 15);            // / (L*K)
    const int l  = (int)((rowBase >> 9) & 63);
    const int k0 = (int)(rowBase & 511);

    const int tid = threadIdx.x;
    const int r  = tid >> 3;                        // row within block, 0..31
    const int j4 = tid & 7;                         // float4 index 0..7 (x2)
    const int k  = k0 + r;

    const int ml = (l == 0) ? 0 : (l - 1);
    const unsigned char mk = mask[((long)w * (PL - 1) + ml) * PK + k];
    int sl;
    if (l == 0) sl = mk ? 1 : 0;
    else        sl = mk ? (l - 1) : l;

    const float4* srcp = (const float4*)(states + (((long)w * PL + sl) * PK + k) * PN);
    float4*       dstp = (float4*)(out + (rowBase + r) * PN);
    dstp[j4]     = srcp[j4];
    dstp[j4 + 8] = srcp[j4 + 8];
}

extern "C" void kernel_launch(void* const* d_in, const int* in_sizes, int n_in,
                              void* d_out, int out_size, void* d_ws, size_t ws_size,
                              hipStream_t stream) {
    const float* states = (const float*)d_in[0];
    const float* Q      = (const float*)d_in[1];
    const float* beta   = (const float*)d_in[2];
    const float* u      = (const float*)d_in[3];

    float* e_out      = (float*)d_out;
    float* new_states = (float*)d_out + (long)PW * PL * PK;

    double* e64 = (double*)d_ws;
    unsigned char* mask = (unsigned char*)d_ws + sizeof(double) * (long)PW * PL * PK;

    // K1: 32 w * 512 chunk-waves = 16384 waves -> 4096 blocks of 256
    energies_kernel<<<4096, 256, 0, stream>>>(states, Q, e_out, e64);

    const int nmask = PW * (PL - 1) * PK;
    mask_kernel<<<(nmask + 255) / 256, 256, 0, stream>>>(e64, beta, u, mask);

    // K3: 1,048,576 rows / 32 per block = 32768 blocks
    swap_kernel<<<32768, 256, 0, stream>>>(states, mask, new_states);
}

// Round 6
// 787.045 us; speedup vs baseline: 1.1787x; 1.1787x over previous
//
#include <hip/hip_runtime.h>
#include <math.h>

#define PW 32
#define PL 64
#define PK 512
#define PN 64
// vectors (replica configurations) total: PW*PL*PK = 1,048,576

// ---------------- Kernel 1: energies ----------------
// Rounds 3-5 lesson: the compiler refuses to keep 64 loop-invariant f64 in
// VGPRs (sinks/spills; VGPR_Count pinned at 76, VALUBusy ~30%). So Q lives
// in LDS as f32 (16 KB/block, architectural residency). Wave-uniform ballot
// mask -> scalar-pipe set-bit iteration (s_ff1/s_and co-issue free); per set
// bit: conflict-free ds_read_b32 + cvt_f64_f32 + add_f64 on 4 independent
// chains. f64 accumulation => same mask decisions as np-f64 reference.
constexpr int VPW = 128;          // vectors per wave
constexpr int BLOCKS = 2048;      // 1M vectors / (4 waves * 128)

__global__ __launch_bounds__(256, 8) void energies_kernel(
    const float* __restrict__ states, const float* __restrict__ Q,
    float* __restrict__ e_out, double* __restrict__ e64)
{
    const int tid  = threadIdx.x;
    const int lane = tid & 63;
    const int wv   = tid >> 6;                 // wave in block, 0..3
    const int w     = blockIdx.x >> 6;         // 64 blocks per w
    const int chunk = blockIdx.x & 63;

    // Stage Q[w] (64x64 f32 = 16 KB) into LDS, float4-vectorized.
    __shared__ float Qs[PN * PN];
    {
        const float4* Qg = (const float4*)(Q + (long)w * PN * PN);
        float4* Qs4 = (float4*)Qs;
#pragma unroll
        for (int k = 0; k < 4; ++k)
            Qs4[tid + k * 256] = Qg[tid + k * 256];
    }
    __syncthreads();

    const long base_v = (long)w * (PL * PK) + (long)chunk * (4 * VPW) + (long)wv * VPW;
    const float* sp = states + base_v * PN + lane;
    const float* QsL = Qs + lane;              // lane's column base

    float s = sp[0];
    for (int t = 0; t < VPW; ++t) {
        float snext = (t + 1 < VPW) ? sp[(long)(t + 1) * PN] : 0.0f;

        unsigned long long mm = __ballot(s != 0.0f);   // wave-uniform (SGPR)
        const int n = __popcll(mm);

        double a0 = 0.0, a1 = 0.0, a2 = 0.0, a3 = 0.0;
        // groups of 4 set bits: 4 independent ds_reads in flight per group
        for (int g = n >> 2; g > 0; --g) {
            const int i0 = __builtin_ctzll(mm); mm &= mm - 1;
            const int i1 = __builtin_ctzll(mm); mm &= mm - 1;
            const int i2 = __builtin_ctzll(mm); mm &= mm - 1;
            const int i3 = __builtin_ctzll(mm); mm &= mm - 1;
            const float f0 = QsL[i0 << 6];
            const float f1 = QsL[i1 << 6];
            const float f2 = QsL[i2 << 6];
            const float f3 = QsL[i3 << 6];
            a0 += (double)f0; a1 += (double)f1;
            a2 += (double)f2; a3 += (double)f3;
        }
        for (int r = n & 3; r > 0; --r) {
            const int i0 = __builtin_ctzll(mm); mm &= mm - 1;
            a0 += (double)QsL[i0 << 6];
        }
        const double colsum = (a0 + a1) + (a2 + a3);

        // lane j contributes only if s_j != 0 ; s is exactly 0.0f or 1.0f
        double e = colsum * (double)s;
#pragma unroll
        for (int off = 32; off > 0; off >>= 1)
            e += __shfl_down(e, off, 64);

        if (lane == 0) {
            e64[base_v + t]   = e;
            e_out[base_v + t] = (float)e;
        }
        s = snext;
    }
}

// ---------------- Kernel 2: exchange masks ----------------
__global__ __launch_bounds__(256) void mask_kernel(
    const double* __restrict__ e64, const float* __restrict__ beta,
    const float* __restrict__ u, unsigned char* __restrict__ mask)
{
    const int idx = blockIdx.x * blockDim.x + threadIdx.x;
    if (idx >= PW * (PL - 1) * PK) return;
    const int k = idx % PK;
    const int m = (idx / PK) % (PL - 1);
    const int w = idx / (PK * (PL - 1));
    const long e1 = ((long)w * PL + m) * PK + k;
    const double db = (double)beta[m + 1] - (double)beta[m];
    const double delta = (e64[e1 + PK] - e64[e1]) * db;
    mask[idx] = ((double)u[idx] < exp(delta)) ? 1 : 0;
}

// ---------------- Kernel 3: masked replica swap ----------------
// new[w,0]   = mask[w,0]   ? s[w,1]   : s[w,0]
// new[w,l>0] = mask[w,l-1] ? s[w,l-1] : s[w,l]
// Block = 32 consecutive rows (same w,l; k 32-aligned). Each thread owns
// row r = tid>>3 and two float4s; loads its own mask byte (8 lanes share one
// byte -> L1 broadcast). No LDS, no barrier.
__global__ __launch_bounds__(256) void swap_kernel(
    const float* __restrict__ states, const unsigned char* __restrict__ mask,
    float* __restrict__ out)
{
    const long rowBase = (long)blockIdx.x * 32;     // (w*L + l)*K + k0
    const int w  = (int)(rowBase >> 15);            // / (L*K)
    const int l  = (int)((rowBase >> 9) & 63);
    const int k0 = (int)(rowBase & 511);

    const int tid = threadIdx.x;
    const int r  = tid >> 3;                        // row within block, 0..31
    const int j4 = tid & 7;                         // float4 index 0..7 (x2)
    const int k  = k0 + r;

    const int ml = (l == 0) ? 0 : (l - 1);
    const unsigned char mk = mask[((long)w * (PL - 1) + ml) * PK + k];
    int sl;
    if (l == 0) sl = mk ? 1 : 0;
    else        sl = mk ? (l - 1) : l;

    const float4* srcp = (const float4*)(states + (((long)w * PL + sl) * PK + k) * PN);
    float4*       dstp = (float4*)(out + (rowBase + r) * PN);
    dstp[j4]     = srcp[j4];
    dstp[j4 + 8] = srcp[j4 + 8];
}

extern "C" void kernel_launch(void* const* d_in, const int* in_sizes, int n_in,
                              void* d_out, int out_size, void* d_ws, size_t ws_size,
                              hipStream_t stream) {
    const float* states = (const float*)d_in[0];
    const float* Q      = (const float*)d_in[1];
    const float* beta   = (const float*)d_in[2];
    const float* u      = (const float*)d_in[3];

    float* e_out      = (float*)d_out;
    float* new_states = (float*)d_out + (long)PW * PL * PK;

    double* e64 = (double*)d_ws;
    unsigned char* mask = (unsigned char*)d_ws + sizeof(double) * (long)PW * PL * PK;

    // K1: 2048 blocks x 4 waves x 128 vectors = 1,048,576 vectors
    energies_kernel<<<BLOCKS, 256, 0, stream>>>(states, Q, e_out, e64);

    const int nmask = PW * (PL - 1) * PK;
    mask_kernel<<<(nmask + 255) / 256, 256, 0, stream>>>(e64, beta, u, mask);

    // K3: 1,048,576 rows / 32 per block = 32768 blocks
    swap_kernel<<<32768, 256, 0, stream>>>(states, mask, new_states);
}

// Round 7
// 504.158 us; speedup vs baseline: 1.8401x; 1.5611x over previous
//
#include <hip/hip_runtime.h>
#include <math.h>

#define PW 32
#define PL 64
#define PK 512
#define PN 64
// vectors total: PW*PL*PK = 1,048,576

typedef int v4i __attribute__((ext_vector_type(4)));

// ---------------- Kernel 1: energies via exact-int i8 MFMA ----------------
// E = s^T Q s, s in {0,1}. R = llrint(Q * 2^33) exact int64; R split into 5
// signed base-256 i8 digits. Per digit: C[j,v] = sum_i digit(R[i,j]) * s_i
// via v_mfma_i32_16x16x64_i8 (i32 exact). Epilogue: sum_j s_j C[j,v], digits
// recombined in int64, scaled 2^-33 in f64. Quantization err <= 2.4e-7 abs
// -> mask-flip expectation ~0.01 over 1M comparisons.
//
// Layouts (C/D verified on HW; A/B standard pattern):
//   A[m][k]: m = lane&15 (=j_local), k = (lane>>4)*16 + b (=i), b=byte 0..15
//   B[k][n]: n = lane&15 (=v_local), k = (lane>>4)*16 + b (=i)
//   C[m][n]: n = lane&15, m = (lane>>4)*4 + reg
//
// MFMA via inline asm (builtin signature for gfx950 i8 uncertain); hazard
// s_nops embedded: s_nop 1 for VALU-write->MFMA-read, 4 back-to-back
// independent MFMAs (~32 cyc) + 2x s_nop 7 before C is read by VALU.

constexpr int TILES_PER_WAVE = 8;   // 16 vectors/tile; 2048 blocks total

__global__ __launch_bounds__(256) void energies_kernel(
    const float* __restrict__ states, const float* __restrict__ Q,
    float* __restrict__ e_out, double* __restrict__ e64)
{
    __shared__ alignas(16) signed char Afrag[20 * 64 * 16];  // [k*4+jt][lane][b]

    const int tid  = threadIdx.x;
    const int lane = tid & 63;
    const int wv   = tid >> 6;
    const int w    = blockIdx.x >> 6;        // 64 blocks per w
    const int blk  = blockIdx.x & 63;

    // ---- build digit fragments of Q[w] in LDS (once per block) ----
    const float* Qw = Q + w * PN * PN;
    for (int e = tid; e < PN * PN; e += 256) {
        const int i = e >> 6, j = e & 63;
        long long R = llrint((double)Qw[e] * 8589934592.0);   // * 2^33
        const int frag_lane = ((i >> 4) << 4) | (j & 15);
        const int jt = j >> 4;
        const int b  = i & 15;
#pragma unroll
        for (int k = 0; k < 5; ++k) {
            const signed char d = (signed char)(R & 0xFF);
            R = (R - d) >> 8;
            Afrag[((k * 4 + jt) * 64 + frag_lane) * 16 + b] = d;
        }
    }
    __syncthreads();

    const v4i* Af = (const v4i*)Afrag;       // [(k*4+jt)*64 + lane]

    const long vw_base = (long)w * (PL * PK)
                       + (long)(blk * 4 + wv) * (16 * TILES_PER_WAVE);

    for (int t = 0; t < TILES_PER_WAVE; ++t) {
        const long vbase = vw_base + (long)t * 16;
        const float* sp = states + vbase * PN + lane;

        // ---- 16 ballots -> this lane keeps mask of vector (lane&15) ----
        unsigned long long mk = 0;
#pragma unroll
        for (int v = 0; v < 16; ++v) {
            const float s = sp[v * PN];                    // coalesced 256B
            const unsigned long long m = __ballot(s != 0.0f);
            mk = ((lane & 15) == v) ? m : mk;              // uniform->cndmask
        }

        // ---- B fragment: bytes b = s_{i=(lane>>4)*16+b} of vector lane&15
        const unsigned int bits16 =
            (unsigned int)(mk >> ((lane >> 4) * 16)) & 0xFFFFu;
        v4i B;
#pragma unroll
        for (int q = 0; q < 4; ++q)
            B[q] = (int)((((bits16 >> (4 * q)) & 0xFu) * 0x00204081u) & 0x01010101u);

        // ---- epilogue row-select bits: j = jt*16 + (lane>>4)*4 + reg ----
        int selb[4];
#pragma unroll
        for (int jt = 0; jt < 4; ++jt)
            selb[jt] = (int)((mk >> (jt * 16 + ((lane >> 4) * 4))) & 0xF);

        long long acc = 0;
#pragma unroll
        for (int k = 0; k < 5; ++k) {
            v4i A0 = Af[(k * 4 + 0) * 64 + lane];
            v4i A1 = Af[(k * 4 + 1) * 64 + lane];
            v4i A2 = Af[(k * 4 + 2) * 64 + lane];
            v4i A3 = Af[(k * 4 + 3) * 64 + lane];
            v4i C0 = {0, 0, 0, 0}, C1 = {0, 0, 0, 0};
            v4i C2 = {0, 0, 0, 0}, C3 = {0, 0, 0, 0};
            asm("s_nop 1\n\t"
                "v_mfma_i32_16x16x64_i8 %0, %4, %8, %0\n\t"
                "v_mfma_i32_16x16x64_i8 %1, %5, %8, %1\n\t"
                "v_mfma_i32_16x16x64_i8 %2, %6, %8, %2\n\t"
                "v_mfma_i32_16x16x64_i8 %3, %7, %8, %3\n\t"
                "s_nop 7\n\t"
                "s_nop 7"
                : "+v"(C0), "+v"(C1), "+v"(C2), "+v"(C3)
                : "v"(A0), "v"(A1), "v"(A2), "v"(A3), "v"(B));
            int ak = 0;
#pragma unroll
            for (int r = 0; r < 4; ++r) {
                ak += ((selb[0] >> r) & 1) * C0[r];
                ak += ((selb[1] >> r) & 1) * C1[r];
                ak += ((selb[2] >> r) & 1) * C2[r];
                ak += ((selb[3] >> r) & 1) * C3[r];
            }
            acc += (long long)ak << (8 * k);
        }

        // ---- reduce the 4 lane-groups holding the same v = lane&15 ----
        acc += __shfl_xor(acc, 16, 64);
        acc += __shfl_xor(acc, 32, 64);

        if (lane < 16) {
            const double e = (double)acc * 0x1p-33;
            e64[vbase + lane]   = e;
            e_out[vbase + lane] = (float)e;
        }
    }
}

// ---------------- Kernel 2: exchange masks ----------------
__global__ __launch_bounds__(256) void mask_kernel(
    const double* __restrict__ e64, const float* __restrict__ beta,
    const float* __restrict__ u, unsigned char* __restrict__ mask)
{
    const int idx = blockIdx.x * blockDim.x + threadIdx.x;
    if (idx >= PW * (PL - 1) * PK) return;
    const int k = idx % PK;
    const int m = (idx / PK) % (PL - 1);
    const int w = idx / (PK * (PL - 1));
    const long e1 = ((long)w * PL + m) * PK + k;
    const double db = (double)beta[m + 1] - (double)beta[m];
    const double delta = (e64[e1 + PK] - e64[e1]) * db;
    mask[idx] = ((double)u[idx] < exp(delta)) ? 1 : 0;
}

// ---------------- Kernel 3: masked replica swap ----------------
// new[w,0]   = mask[w,0]   ? s[w,1]   : s[w,0]
// new[w,l>0] = mask[w,l-1] ? s[w,l-1] : s[w,l]
__global__ __launch_bounds__(256) void swap_kernel(
    const float* __restrict__ states, const unsigned char* __restrict__ mask,
    float* __restrict__ out)
{
    const long rowBase = (long)blockIdx.x * 32;     // (w*L + l)*K + k0
    const int w  = (int)(rowBase >> 15);            // / (L*K)
    const int l  = (int)((rowBase >> 9) & 63);
    const int k0 = (int)(rowBase & 511);

    const int tid = threadIdx.x;
    const int r  = tid >> 3;                        // row within block, 0..31
    const int j4 = tid & 7;                         // float4 index 0..7 (x2)
    const int k  = k0 + r;

    const int ml = (l == 0) ? 0 : (l - 1);
    const unsigned char mk = mask[((long)w * (PL - 1) + ml) * PK + k];
    int sl;
    if (l == 0) sl = mk ? 1 : 0;
    else        sl = mk ? (l - 1) : l;

    const float4* srcp = (const float4*)(states + (((long)w * PL + sl) * PK + k) * PN);
    float4*       dstp = (float4*)(out + (rowBase + r) * PN);
    dstp[j4]     = srcp[j4];
    dstp[j4 + 8] = srcp[j4 + 8];
}

extern "C" void kernel_launch(void* const* d_in, const int* in_sizes, int n_in,
                              void* d_out, int out_size, void* d_ws, size_t ws_size,
                              hipStream_t stream) {
    const float* states = (const float*)d_in[0];
    const float* Q      = (const float*)d_in[1];
    const float* beta   = (const float*)d_in[2];
    const float* u      = (const float*)d_in[3];

    float* e_out      = (float*)d_out;
    float* new_states = (float*)d_out + (long)PW * PL * PK;

    double* e64 = (double*)d_ws;
    unsigned char* mask = (unsigned char*)d_ws + sizeof(double) * (long)PW * PL * PK;

    // K1: 2048 blocks; block = 4 waves; wave = 8 tiles x 16 vectors
    //     -> 2048 * 4 * 128 = 1,048,576 vectors
    energies_kernel<<<2048, 256, 0, stream>>>(states, Q, e_out, e64);

    const int nmask = PW * (PL - 1) * PK;
    mask_kernel<<<(nmask + 255) / 256, 256, 0, stream>>>(e64, beta, u, mask);

    // K3: 1,048,576 rows / 32 per block = 32768 blocks
    swap_kernel<<<32768, 256, 0, stream>>>(states, mask, new_states);
}